// Round 3
// baseline (952.387 us; speedup 1.0000x reference)
//
#include <hip/hip_runtime.h>

// RecurrentActorCritic B=512,T=512,S=64,H=128,A=8 (fp32 I/O).
// R13 = R12 resubmit (container infra failure, kernel never ran).
// p2 matvec -> MFMA, gates fused in-register. Old p2 was LDS-pipe
// bound: 96 broadcast ds_read_b128/interval (~950cyc) for hsh. New p2:
// Whh held in VGPRs (A-frags, 48 reg/wave); wave w owns n-tiles
// {w,w+8,w+16} so gh[d],gh[d+128],gh[d+256] land in the SAME lane/reg j
// -> gates in-register, no gh LDS round-trip, hprev lane-resident.
// h double-buffered (hsh16[2]) -> ONE barrier/step (512 vs 1024).
// B-frag = h cols (chains in cols 0,1; other cols replicated, discarded).
// Bias folded into MFMA C-init. Bursts+staging on waves 8-11 (j=1..6,
// staging write at j=15 into opposite buffer before BAR).
// p1 byte-identical to R11 (MFMA GEMM, ~220us).

typedef _Float16 h2t __attribute__((ext_vector_type(2)));
typedef _Float16 f16x4 __attribute__((ext_vector_type(4)));
typedef _Float16 f16x8 __attribute__((ext_vector_type(8)));
typedef float f32x4 __attribute__((ext_vector_type(4)));

__device__ __forceinline__ unsigned short hpk(float v) {
    return __builtin_bit_cast(unsigned short, (_Float16)v);
}

// LDS-only barrier: drain ds ops, leave global loads/stores in flight.
#define BAR() __asm__ volatile("s_waitcnt lgkmcnt(0)\n\ts_barrier" ::: "memory")

#define BB 512
#define TT 512
#define SS 64
#define HH 128
#define AA 8
#define CK 16
#define NCK (TT / CK)
#define VALO (BB * TT * AA)
#define HFIN (VALO + BB * TT)

// ======================= PHASE 1 (MFMA, unchanged from R11) =======================
// 4096 blocks x 256 threads; 64 rows (one b,t-tile) per block.
__global__ void __launch_bounds__(256, 2) p1_kernel(
    const float* __restrict__ x,   const float* __restrict__ Wf,
    const float* __restrict__ bfe, const float* __restrict__ gf,
    const float* __restrict__ btf, const float* __restrict__ Wih,
    const float* __restrict__ bih, unsigned short* __restrict__ gxws)
{
    const int tid = threadIdx.x;
    const int wv  = tid >> 6;
    const int l   = tid & 63;
    const int lo  = l & 15;
    const int hi  = l >> 4;
    const size_t m0 = (size_t)blockIdx.x * 64;

    __shared__ __align__(16) _Float16 xh[64][72];
    __shared__ __align__(16) float    fb[64][132];
    __shared__ __align__(16) _Float16 zh[64][136];

    // ---- stage x tile: 64 rows x 64 f32 -> fp16 LDS ----
    {
        const int r  = tid >> 2;
        const int c0 = (tid & 3) << 4;
        const float4* px = (const float4*)(x + (m0 + (size_t)r) * SS + c0);
        float4 a = px[0], b = px[1], c = px[2], d = px[3];
        f16x8 h0, h1;
        h0[0]=(_Float16)a.x; h0[1]=(_Float16)a.y; h0[2]=(_Float16)a.z; h0[3]=(_Float16)a.w;
        h0[4]=(_Float16)b.x; h0[5]=(_Float16)b.y; h0[6]=(_Float16)b.z; h0[7]=(_Float16)b.w;
        h1[0]=(_Float16)c.x; h1[1]=(_Float16)c.y; h1[2]=(_Float16)c.z; h1[3]=(_Float16)c.w;
        h1[4]=(_Float16)d.x; h1[5]=(_Float16)d.y; h1[6]=(_Float16)d.z; h1[7]=(_Float16)d.w;
        *(f16x8*)&xh[r][c0]     = h0;
        *(f16x8*)&xh[r][c0 + 8] = h1;
    }
    __syncthreads();

    // ---- GEMM1: fb = x @ Wf^T + bfe  (M=64, N=128 = 4 waves x 32, K=64) ----
    {
        const int n0 = wv << 5;
        f32x4 acc[4][2];
        #pragma unroll
        for (int mt = 0; mt < 4; ++mt)
            #pragma unroll
            for (int nt = 0; nt < 2; ++nt) {
                acc[mt][nt][0]=0.f; acc[mt][nt][1]=0.f;
                acc[mt][nt][2]=0.f; acc[mt][nt][3]=0.f;
            }
        #pragma unroll
        for (int kk = 0; kk < 2; ++kk) {
            f16x8 bf[2];
            #pragma unroll
            for (int nt = 0; nt < 2; ++nt) {
                const float4* wp = (const float4*)(Wf + (size_t)(n0 + nt*16 + lo) * SS + kk*32 + hi*8);
                float4 w0 = wp[0], w1 = wp[1];
                f16x8 t;
                t[0]=(_Float16)w0.x; t[1]=(_Float16)w0.y; t[2]=(_Float16)w0.z; t[3]=(_Float16)w0.w;
                t[4]=(_Float16)w1.x; t[5]=(_Float16)w1.y; t[6]=(_Float16)w1.z; t[7]=(_Float16)w1.w;
                bf[nt] = t;
            }
            #pragma unroll
            for (int mt = 0; mt < 4; ++mt) {
                f16x8 af = *(const f16x8*)&xh[mt*16 + lo][kk*32 + hi*8];
                acc[mt][0] = __builtin_amdgcn_mfma_f32_16x16x32_f16(af, bf[0], acc[mt][0], 0, 0, 0);
                acc[mt][1] = __builtin_amdgcn_mfma_f32_16x16x32_f16(af, bf[1], acc[mt][1], 0, 0, 0);
            }
        }
        const float b0 = bfe[n0 + lo];
        const float b1 = bfe[n0 + 16 + lo];
        #pragma unroll
        for (int mt = 0; mt < 4; ++mt)
            #pragma unroll
            for (int j = 0; j < 4; ++j) {
                fb[mt*16 + hi*4 + j][n0 + lo]      = acc[mt][0][j] + b0;
                fb[mt*16 + hi*4 + j][n0 + 16 + lo] = acc[mt][1][j] + b1;
            }
    }
    __syncthreads();

    // ---- LN + ReLU -> zh fp16  (4 threads per row, shfl_xor combine) ----
    {
        const int r = tid >> 2;
        const int q = tid & 3;
        const float4* pf = (const float4*)&fb[r][q << 5];
        float4 v[8];
        float s = 0.f, ss = 0.f;
        #pragma unroll
        for (int i = 0; i < 8; ++i) {
            float4 t = pf[i]; v[i] = t;
            s  += (t.x + t.y) + (t.z + t.w);
            ss += (t.x*t.x + t.y*t.y) + (t.z*t.z + t.w*t.w);
        }
        s  += __shfl_xor(s, 1);  s  += __shfl_xor(s, 2);
        ss += __shfl_xor(ss, 1); ss += __shfl_xor(ss, 2);
        const float mu   = s * (1.f / 128.f);
        const float rstd = rsqrtf(ss * (1.f / 128.f) - mu * mu + 1e-5f);
        const float4* pg = (const float4*)(gf  + (q << 5));
        const float4* pb = (const float4*)(btf + (q << 5));
        #pragma unroll
        for (int i = 0; i < 8; ++i) {
            float4 g = pg[i], bb = pb[i], t = v[i];
            h2t pA, pB;
            pA.x = (_Float16)fmaxf((t.x - mu) * rstd * g.x + bb.x, 0.f);
            pA.y = (_Float16)fmaxf((t.y - mu) * rstd * g.y + bb.y, 0.f);
            pB.x = (_Float16)fmaxf((t.z - mu) * rstd * g.z + bb.z, 0.f);
            pB.y = (_Float16)fmaxf((t.w - mu) * rstd * g.w + bb.w, 0.f);
            uint2 u;
            u.x = __builtin_bit_cast(unsigned int, pA);
            u.y = __builtin_bit_cast(unsigned int, pB);
            *(uint2*)&zh[r][(q << 5) + i * 4] = u;
        }
    }
    __syncthreads();

    // ---- GEMM2 (transposed): D[n][m] = sum_k Wih[n][k] z[m][k] ----
    {
        const int n0 = wv * 96;
        f16x8 bz[4][4];
        #pragma unroll
        for (int mt = 0; mt < 4; ++mt)
            #pragma unroll
            for (int ks = 0; ks < 4; ++ks)
                bz[mt][ks] = *(const f16x8*)&zh[mt*16 + lo][ks*32 + hi*8];
        #pragma unroll
        for (int nt = 0; nt < 6; ++nt) {
            const int nb = n0 + nt * 16;
            const float4 b4 = *(const float4*)(bih + nb + (hi << 2));
            const float* wr = Wih + (size_t)(nb + lo) * HH;
            f32x4 acc[4];
            #pragma unroll
            for (int mt = 0; mt < 4; ++mt) {
                acc[mt][0]=0.f; acc[mt][1]=0.f; acc[mt][2]=0.f; acc[mt][3]=0.f;
            }
            #pragma unroll
            for (int ks = 0; ks < 4; ++ks) {
                const float4* wp = (const float4*)(wr + ks*32 + hi*8);
                float4 w0 = wp[0], w1 = wp[1];
                f16x8 af;
                af[0]=(_Float16)w0.x; af[1]=(_Float16)w0.y; af[2]=(_Float16)w0.z; af[3]=(_Float16)w0.w;
                af[4]=(_Float16)w1.x; af[5]=(_Float16)w1.y; af[6]=(_Float16)w1.z; af[7]=(_Float16)w1.w;
                #pragma unroll
                for (int mt = 0; mt < 4; ++mt)
                    acc[mt] = __builtin_amdgcn_mfma_f32_16x16x32_f16(af, bz[mt][ks], acc[mt], 0, 0, 0);
            }
            #pragma unroll
            for (int mt = 0; mt < 4; ++mt) {
                h2t pA, pB;
                pA.x = (_Float16)(acc[mt][0] + b4.x);
                pA.y = (_Float16)(acc[mt][1] + b4.y);
                pB.x = (_Float16)(acc[mt][2] + b4.z);
                pB.y = (_Float16)(acc[mt][3] + b4.w);
                uint2 u;
                u.x = __builtin_bit_cast(unsigned int, pA);
                u.y = __builtin_bit_cast(unsigned int, pB);
                *(uint2*)(gxws + (m0 + (size_t)(mt*16 + lo)) * 384 + nb + (hi << 2)) = u;
            }
        }
    }
}

// ======================= PHASE 2 (MFMA recurrence) =======================
// 256 blocks x 768 threads. Waves 0-7: mfma matvec + fused gates (2 chains,
// chain = lo&1). Waves 8-11: gx staging + LN/head bursts.
__global__ void __launch_bounds__(768, 3) p2_kernel(
    const float* __restrict__ hx,  const int* __restrict__ done,
    const float* __restrict__ Whh, const float* __restrict__ bhh,
    const float* __restrict__ gr,  const float* __restrict__ btr,
    const float* __restrict__ Wp,  const float* __restrict__ bp,
    const float* __restrict__ Wv,  const float* __restrict__ bv,
    const unsigned short* __restrict__ gxws, float* __restrict__ out)
{
    const int tid = threadIdx.x;
    const int blk = blockIdx.x;

    __shared__ __align__(16) _Float16 hsh16[2][2][160];      // [buf][chain][pad160]
    __shared__ __align__(16) _Float16 gxb[2][2][CK][384];    // [chain][buf][t][3H] 48 KB
    __shared__ __align__(16) float hnr[2][32][132];          // 33.8 KB
    __shared__ __align__(16) float ylr[2][CK][132];          // 16.9 KB
    __shared__ __align__(16) float wpl[9][132];
    __shared__ float bpl[9];
    __shared__ __align__(16) float grl[HH], btrl[HH];
    __shared__ float musd[2][CK][2];
    __shared__ int dsh[2][TT];

    const int l  = tid & 63;
    const int lo = l & 15;
    const int hi = l >> 4;
    const int wv = tid >> 6;          // 0..11
    const int Y  = lo & 1;            // chain owned by this mfma lane
    const int d0 = (wv & 7) * 16 + hi * 4;

    // ---- mfma-wave persistent state: Whh A-frags + bias + hprev ----
    f16x8 aW[3][4];
    f32x4 bias[3];
    float hp[4];
    if (tid < 512) {
        #pragma unroll
        for (int q = 0; q < 3; ++q) {
            const float* wr = Whh + (size_t)(q * 128 + (wv & 7) * 16 + lo) * HH;
            #pragma unroll
            for (int ks = 0; ks < 4; ++ks) {
                const float4* wp = (const float4*)(wr + ks * 32 + hi * 8);
                float4 w0 = wp[0], w1 = wp[1];
                f16x8 t;
                t[0]=(_Float16)w0.x; t[1]=(_Float16)w0.y; t[2]=(_Float16)w0.z; t[3]=(_Float16)w0.w;
                t[4]=(_Float16)w1.x; t[5]=(_Float16)w1.y; t[6]=(_Float16)w1.z; t[7]=(_Float16)w1.w;
                aW[q][ks] = t;
            }
            bias[q] = *(const f32x4*)&bhh[q * 128 + (wv & 7) * 16 + hi * 4];
        }
        const float4 h4 = *(const float4*)&hx[(size_t)(2 * blk + Y) * HH + d0];
        hp[0]=h4.x; hp[1]=h4.y; hp[2]=h4.z; hp[3]=h4.w;
    }

    if (tid < 256) {
        const int Yc = tid >> 7, d = tid & 127;
        hsh16[0][Yc][d] = (_Float16)hx[(size_t)(2 * blk + Yc) * HH + d];
    }
    if (tid < HH) { grl[tid] = gr[tid]; btrl[tid] = btr[tid]; }
    for (int idx = tid; idx < 9 * HH; idx += 768) {
        int row = idx >> 7, col = idx & 127;
        wpl[row][col] = (row < 8) ? Wp[row * HH + col] : Wv[col];
    }
    if (tid < 9) bpl[tid] = (tid < 8) ? bp[tid] : bv[0];
    for (int idx = tid; idx < 2 * TT; idx += 768)
        dsh[idx >> 9][idx & 511] = done[(2 * blk + (idx >> 9)) * TT + (idx & 511)];

    // ---- gx staging: waves 8-11 (256 threads), 6 ushort4/chain/chunk ----
    const bool isStg = (tid >= 512);
    const int  sSt = tid - 512;
    const unsigned short* baseA = gxws + (size_t)(2 * blk + 0) * TT * 384;
    const unsigned short* baseB = gxws + (size_t)(2 * blk + 1) * TT * 384;
    ushort4 rA0, rA1, rA2, rA3, rA4, rA5, rB0, rB1, rB2, rB3, rB4, rB5;
    if (isStg) {   // chunk 0 -> buffer 0
        const ushort4* ca = (const ushort4*)baseA;
        const ushort4* cb = (const ushort4*)baseB;
        rA0=ca[0*256+sSt]; rA1=ca[1*256+sSt]; rA2=ca[2*256+sSt];
        rA3=ca[3*256+sSt]; rA4=ca[4*256+sSt]; rA5=ca[5*256+sSt];
        rB0=cb[0*256+sSt]; rB1=cb[1*256+sSt]; rB2=cb[2*256+sSt];
        rB3=cb[3*256+sSt]; rB4=cb[4*256+sSt]; rB5=cb[5*256+sSt];
        ushort4* ga = (ushort4*)&gxb[0][0][0][0];
        ushort4* gb = (ushort4*)&gxb[1][0][0][0];
        ga[0*256+sSt]=rA0; ga[1*256+sSt]=rA1; ga[2*256+sSt]=rA2;
        ga[3*256+sSt]=rA3; ga[4*256+sSt]=rA4; ga[5*256+sSt]=rA5;
        gb[0*256+sSt]=rB0; gb[1*256+sSt]=rB1; gb[2*256+sSt]=rB2;
        gb[3*256+sSt]=rB3; gb[4*256+sSt]=rB4; gb[5*256+sSt]=rB5;
    }
    __syncthreads();

    const int s2 = tid - 512;

    // ---- bursts for chain Y, chunk cm1 (zero cross-lane) ----
    #define BSTAT(Y_, CM1, SL) { \
        int row_ = (((CM1) * CK + (SL)) & 31); \
        const float4* ph_ = (const float4*)hnr[Y_][row_]; \
        float sv_ = 0.f, qv_ = 0.f; \
        for (int k2 = 0; k2 < 32; ++k2) { float4 v_ = ph_[k2]; \
            sv_ += (v_.x + v_.y) + (v_.z + v_.w); \
            qv_ += (v_.x*v_.x + v_.y*v_.y) + (v_.z*v_.z + v_.w*v_.w); } \
        float mu_ = sv_ * (1.f / 128.f); \
        musd[Y_][SL][0] = mu_; \
        musd[Y_][SL][1] = rsqrtf(qv_ * (1.f / 128.f) - mu_ * mu_ + 1e-5f); }

    #define BY(Y_, CM1, SL) { \
        int t16_ = (SL) >> 4, k_ = (SL) & 15; \
        int row_ = (((CM1) * CK + t16_) & 31); \
        float mu_ = musd[Y_][t16_][0], rs_ = musd[Y_][t16_][1]; \
        const float4* ph_ = (const float4*)&hnr[Y_][row_][k_ * 8]; \
        const float4* pg_ = (const float4*)&grl[k_ * 8]; \
        const float4* pb_ = (const float4*)&btrl[k_ * 8]; \
        float4 h0_ = ph_[0], h1_ = ph_[1], g0_ = pg_[0], g1_ = pg_[1], b0_ = pb_[0], b1_ = pb_[1]; \
        float4 y0_, y1_; \
        y0_.x = (h0_.x - mu_) * rs_ * g0_.x + b0_.x; \
        y0_.y = (h0_.y - mu_) * rs_ * g0_.y + b0_.y; \
        y0_.z = (h0_.z - mu_) * rs_ * g0_.z + b0_.z; \
        y0_.w = (h0_.w - mu_) * rs_ * g0_.w + b0_.w; \
        y1_.x = (h1_.x - mu_) * rs_ * g1_.x + b1_.x; \
        y1_.y = (h1_.y - mu_) * rs_ * g1_.y + b1_.y; \
        y1_.z = (h1_.z - mu_) * rs_ * g1_.z + b1_.z; \
        y1_.w = (h1_.w - mu_) * rs_ * g1_.w + b1_.w; \
        ((float4*)&ylr[Y_][t16_][k_ * 8])[0] = y0_; \
        ((float4*)&ylr[Y_][t16_][k_ * 8])[1] = y1_; }

    #define BHEAD(Y_, CM1, SL) { \
        int t16_ = (SL) / 9, hd_ = (SL) - t16_ * 9; \
        const float4* py_ = (const float4*)ylr[Y_][t16_]; \
        const float4* pw_ = (const float4*)wpl[hd_]; \
        float acc_ = 0.f; \
        for (int k2 = 0; k2 < 32; ++k2) { float4 yv_ = py_[k2], wv_ = pw_[k2]; \
            acc_ += (yv_.x*wv_.x + yv_.y*wv_.y) + (yv_.z*wv_.z + yv_.w*wv_.w); } \
        int t_ = (CM1) * CK + t16_; \
        float o_ = acc_ + bpl[hd_]; \
        if (hd_ < 8) out[((size_t)(2 * blk + (Y_)) * TT + t_) * AA + hd_] = o_; \
        else         out[VALO + (2 * blk + (Y_)) * TT + t_] = o_; }

    for (int c = 0; c < NCK; ++c) {
        if (isStg && c + 1 < NCK) {   // issue next-chunk loads (16-step slack)
            const ushort4* ca = (const ushort4*)(baseA + (size_t)(c + 1) * CK * 384);
            const ushort4* cb = (const ushort4*)(baseB + (size_t)(c + 1) * CK * 384);
            rA0=ca[0*256+sSt]; rA1=ca[1*256+sSt]; rA2=ca[2*256+sSt];
            rA3=ca[3*256+sSt]; rA4=ca[4*256+sSt]; rA5=ca[5*256+sSt];
            rB0=cb[0*256+sSt]; rB1=cb[1*256+sSt]; rB2=cb[2*256+sSt];
            rB3=cb[3*256+sSt]; rB4=cb[4*256+sSt]; rB5=cb[5*256+sSt];
        }
        for (int j = 0; j < CK; ++j) {
            const int t = c * CK + j;
            if (tid < 512) {
                // B-frags: h (both chains) from current buffer
                const _Float16* hb = hsh16[t & 1][Y];
                f16x8 B0 = *(const f16x8*)&hb[0  + hi*8];
                f16x8 B1 = *(const f16x8*)&hb[32 + hi*8];
                f16x8 B2 = *(const f16x8*)&hb[64 + hi*8];
                f16x8 B3 = *(const f16x8*)&hb[96 + hi*8];
                const _Float16* gxp = gxb[Y][c & 1][j];
                f16x4 g0 = *(const f16x4*)&gxp[d0];
                f16x4 g1 = *(const f16x4*)&gxp[128 + d0];
                f16x4 g2 = *(const f16x4*)&gxp[256 + d0];
                const float mask = dsh[Y][t] ? 0.f : 1.f;
                f32x4 a0 = bias[0], a1 = bias[1], a2 = bias[2];
                a0 = __builtin_amdgcn_mfma_f32_16x16x32_f16(aW[0][0], B0, a0, 0, 0, 0);
                a1 = __builtin_amdgcn_mfma_f32_16x16x32_f16(aW[1][0], B0, a1, 0, 0, 0);
                a2 = __builtin_amdgcn_mfma_f32_16x16x32_f16(aW[2][0], B0, a2, 0, 0, 0);
                a0 = __builtin_amdgcn_mfma_f32_16x16x32_f16(aW[0][1], B1, a0, 0, 0, 0);
                a1 = __builtin_amdgcn_mfma_f32_16x16x32_f16(aW[1][1], B1, a1, 0, 0, 0);
                a2 = __builtin_amdgcn_mfma_f32_16x16x32_f16(aW[2][1], B1, a2, 0, 0, 0);
                a0 = __builtin_amdgcn_mfma_f32_16x16x32_f16(aW[0][2], B2, a0, 0, 0, 0);
                a1 = __builtin_amdgcn_mfma_f32_16x16x32_f16(aW[1][2], B2, a1, 0, 0, 0);
                a2 = __builtin_amdgcn_mfma_f32_16x16x32_f16(aW[2][2], B2, a2, 0, 0, 0);
                a0 = __builtin_amdgcn_mfma_f32_16x16x32_f16(aW[0][3], B3, a0, 0, 0, 0);
                a1 = __builtin_amdgcn_mfma_f32_16x16x32_f16(aW[1][3], B3, a1, 0, 0, 0);
                a2 = __builtin_amdgcn_mfma_f32_16x16x32_f16(aW[2][3], B3, a2, 0, 0, 0);
                // fused gates: lane owns d = d0..d0+3 of chain Y
                float hnA[4], hmA[4];
                #pragma unroll
                for (int jj = 0; jj < 4; ++jj) {
                    float xr = (float)g0[jj] + a0[jj];
                    float xz = (float)g1[jj] + a1[jj];
                    float r_ = 1.f / (1.f + __expf(-xr));
                    float u_ = 1.f / (1.f + __expf(-xz));
                    float a_ = (float)g2[jj] + r_ * a2[jj];
                    a_ = fminf(fmaxf(a_, -20.f), 20.f);
                    float e2 = __expf(2.f * a_);
                    float nn = (e2 - 1.f) / (e2 + 1.f);
                    float hnew = (1.f - u_) * nn + u_ * hp[jj];
                    float hm = hnew * mask;
                    hp[jj] = hm;
                    hnA[jj] = hnew;
                    hmA[jj] = hm;
                }
                if (lo < 2) {
                    float4 hn4 = make_float4(hnA[0], hnA[1], hnA[2], hnA[3]);
                    *(float4*)&hnr[Y][t & 31][d0] = hn4;
                    h2t p0, p1v;
                    p0.x  = (_Float16)hmA[0]; p0.y  = (_Float16)hmA[1];
                    p1v.x = (_Float16)hmA[2]; p1v.y = (_Float16)hmA[3];
                    uint2 u;
                    u.x = __builtin_bit_cast(unsigned int, p0);
                    u.y = __builtin_bit_cast(unsigned int, p1v);
                    *(uint2*)&hsh16[(t + 1) & 1][Y][d0] = u;
                    if (t == TT - 1) {
                        float4 hm4 = make_float4(hmA[0], hmA[1], hmA[2], hmA[3]);
                        *(float4*)&out[HFIN + (size_t)(2 * blk + Y) * HH + d0] = hm4;
                    }
                }
            } else if (c >= 1) {
                if      (j == 1 && s2 < CK)  BSTAT(0, c - 1, s2)
                else if (j == 2 && s2 < CK)  BSTAT(1, c - 1, s2)
                else if (j == 3)             BY(0, c - 1, s2)
                else if (j == 4)             BY(1, c - 1, s2)
                else if (j == 5 && s2 < 144) BHEAD(0, c - 1, s2)
                else if (j == 6 && s2 < 144) BHEAD(1, c - 1, s2)
            }
            if (isStg && j == CK - 1 && c + 1 < NCK) {  // write into opposite buffer
                const int nb = (c + 1) & 1;
                ushort4* ga = (ushort4*)&gxb[0][nb][0][0];
                ushort4* gb = (ushort4*)&gxb[1][nb][0][0];
                ga[0*256+sSt]=rA0; ga[1*256+sSt]=rA1; ga[2*256+sSt]=rA2;
                ga[3*256+sSt]=rA3; ga[4*256+sSt]=rA4; ga[5*256+sSt]=rA5;
                gb[0*256+sSt]=rB0; gb[1*256+sSt]=rB1; gb[2*256+sSt]=rB2;
                gb[3*256+sSt]=rB3; gb[4*256+sSt]=rB4; gb[5*256+sSt]=rB5;
            }
            BAR();
        }
    }

    // ===== epilogue: bursts for chunk NCK-1 =====
    if (tid >= 512) {
        if (s2 < CK)            BSTAT(0, NCK - 1, s2)
        else if (s2 < 2 * CK)   BSTAT(1, NCK - 1, s2 - CK)
    }
    BAR();
    if (tid >= 512) BY(0, NCK - 1, s2)
    if (tid >= 256 && tid < 512) { int s3 = tid - 256; BY(1, NCK - 1, s3) }
    BAR();
    if (tid >= 512 && s2 < 144) BHEAD(0, NCK - 1, s2)
    if (tid >= 256 && tid < 400) { int s3 = tid - 256; BHEAD(1, NCK - 1, s3) }
}

extern "C" void kernel_launch(void* const* d_in, const int* in_sizes, int n_in,
                              void* d_out, int out_size, void* d_ws, size_t ws_size,
                              hipStream_t stream) {
    const float* x   = (const float*)d_in[0];
    const float* hx  = (const float*)d_in[1];
    const int*   dn  = (const int*)d_in[2];
    const float* Wf  = (const float*)d_in[3];
    const float* bfe = (const float*)d_in[4];
    const float* gf  = (const float*)d_in[5];
    const float* btf = (const float*)d_in[6];
    const float* Wih = (const float*)d_in[7];
    const float* Whh = (const float*)d_in[8];
    const float* bih = (const float*)d_in[9];
    const float* bhh = (const float*)d_in[10];
    const float* gr  = (const float*)d_in[11];
    const float* btr = (const float*)d_in[12];
    const float* Wp  = (const float*)d_in[13];
    const float* bp  = (const float*)d_in[14];
    const float* Wv  = (const float*)d_in[15];
    const float* bv  = (const float*)d_in[16];
    float* out = (float*)d_out;

    unsigned short* gxws = (unsigned short*)d_ws;   // 201.3 MB gx buffer
    hipLaunchKernelGGL(p1_kernel, dim3(BB * TT / 64), dim3(256), 0, stream,
                       x, Wf, bfe, gf, btf, Wih, bih, gxws);
    hipLaunchKernelGGL(p2_kernel, dim3(BB / 2), dim3(768), 0, stream,
                       hx, dn, Whh, bhh, gr, btr, Wp, bp, Wv, bv, gxws, out);
}

// Round 4
// 680.582 us; speedup vs baseline: 1.3994x; 1.3994x over previous
//
#include <hip/hip_runtime.h>

// RecurrentActorCritic B=512,T=512,S=64,H=128,A=8 (fp32 I/O).
// R14: dual-rate split. R13 post-mortem: gates ran redundantly on 8 waves
// with full-precision divisions (VALUBusy 65%), and LN/head bursts sat
// inside the per-step barrier (18.9M bank-conflict cyc). Now:
//   p2 = serial loop ONLY: ds_read h -> 12 MFMA -> gates(rcpf) -> store.
//        hnew(pre-mask) streamed to ws (fp32, reusing gxws slot: 768B/t
//        holds 512B hraw; gx for that t already consumed; p1 rewrites).
//   p3 = LN + 9-head projection, 4096 blocks wide. Interleaved-quarter
//        col mapping (thread q owns chunks c%4==q) -> conflict-free wpl
//        reads (q*128B stride would alias banks) + coalesced global.
// p1 byte-identical to R11 (MFMA GEMM, ~220us).

typedef _Float16 h2t __attribute__((ext_vector_type(2)));
typedef _Float16 f16x4 __attribute__((ext_vector_type(4)));
typedef _Float16 f16x8 __attribute__((ext_vector_type(8)));
typedef float f32x4 __attribute__((ext_vector_type(4)));

__device__ __forceinline__ unsigned short hpk(float v) {
    return __builtin_bit_cast(unsigned short, (_Float16)v);
}

// LDS-only barrier: drain ds ops, leave global loads/stores in flight.
#define BAR() __asm__ volatile("s_waitcnt lgkmcnt(0)\n\ts_barrier" ::: "memory")

#define BB 512
#define TT 512
#define SS 64
#define HH 128
#define AA 8
#define CK 16
#define NCK (TT / CK)
#define VALO (BB * TT * AA)
#define HFIN (VALO + BB * TT)

// ======================= PHASE 1 (MFMA, unchanged from R11) =======================
__global__ void __launch_bounds__(256, 2) p1_kernel(
    const float* __restrict__ x,   const float* __restrict__ Wf,
    const float* __restrict__ bfe, const float* __restrict__ gf,
    const float* __restrict__ btf, const float* __restrict__ Wih,
    const float* __restrict__ bih, unsigned short* __restrict__ gxws)
{
    const int tid = threadIdx.x;
    const int wv  = tid >> 6;
    const int l   = tid & 63;
    const int lo  = l & 15;
    const int hi  = l >> 4;
    const size_t m0 = (size_t)blockIdx.x * 64;

    __shared__ __align__(16) _Float16 xh[64][72];
    __shared__ __align__(16) float    fb[64][132];
    __shared__ __align__(16) _Float16 zh[64][136];

    {
        const int r  = tid >> 2;
        const int c0 = (tid & 3) << 4;
        const float4* px = (const float4*)(x + (m0 + (size_t)r) * SS + c0);
        float4 a = px[0], b = px[1], c = px[2], d = px[3];
        f16x8 h0, h1;
        h0[0]=(_Float16)a.x; h0[1]=(_Float16)a.y; h0[2]=(_Float16)a.z; h0[3]=(_Float16)a.w;
        h0[4]=(_Float16)b.x; h0[5]=(_Float16)b.y; h0[6]=(_Float16)b.z; h0[7]=(_Float16)b.w;
        h1[0]=(_Float16)c.x; h1[1]=(_Float16)c.y; h1[2]=(_Float16)c.z; h1[3]=(_Float16)c.w;
        h1[4]=(_Float16)d.x; h1[5]=(_Float16)d.y; h1[6]=(_Float16)d.z; h1[7]=(_Float16)d.w;
        *(f16x8*)&xh[r][c0]     = h0;
        *(f16x8*)&xh[r][c0 + 8] = h1;
    }
    __syncthreads();

    {
        const int n0 = wv << 5;
        f32x4 acc[4][2];
        #pragma unroll
        for (int mt = 0; mt < 4; ++mt)
            #pragma unroll
            for (int nt = 0; nt < 2; ++nt) {
                acc[mt][nt][0]=0.f; acc[mt][nt][1]=0.f;
                acc[mt][nt][2]=0.f; acc[mt][nt][3]=0.f;
            }
        #pragma unroll
        for (int kk = 0; kk < 2; ++kk) {
            f16x8 bf[2];
            #pragma unroll
            for (int nt = 0; nt < 2; ++nt) {
                const float4* wp = (const float4*)(Wf + (size_t)(n0 + nt*16 + lo) * SS + kk*32 + hi*8);
                float4 w0 = wp[0], w1 = wp[1];
                f16x8 t;
                t[0]=(_Float16)w0.x; t[1]=(_Float16)w0.y; t[2]=(_Float16)w0.z; t[3]=(_Float16)w0.w;
                t[4]=(_Float16)w1.x; t[5]=(_Float16)w1.y; t[6]=(_Float16)w1.z; t[7]=(_Float16)w1.w;
                bf[nt] = t;
            }
            #pragma unroll
            for (int mt = 0; mt < 4; ++mt) {
                f16x8 af = *(const f16x8*)&xh[mt*16 + lo][kk*32 + hi*8];
                acc[mt][0] = __builtin_amdgcn_mfma_f32_16x16x32_f16(af, bf[0], acc[mt][0], 0, 0, 0);
                acc[mt][1] = __builtin_amdgcn_mfma_f32_16x16x32_f16(af, bf[1], acc[mt][1], 0, 0, 0);
            }
        }
        const float b0 = bfe[n0 + lo];
        const float b1 = bfe[n0 + 16 + lo];
        #pragma unroll
        for (int mt = 0; mt < 4; ++mt)
            #pragma unroll
            for (int j = 0; j < 4; ++j) {
                fb[mt*16 + hi*4 + j][n0 + lo]      = acc[mt][0][j] + b0;
                fb[mt*16 + hi*4 + j][n0 + 16 + lo] = acc[mt][1][j] + b1;
            }
    }
    __syncthreads();

    {
        const int r = tid >> 2;
        const int q = tid & 3;
        const float4* pf = (const float4*)&fb[r][q << 5];
        float4 v[8];
        float s = 0.f, ss = 0.f;
        #pragma unroll
        for (int i = 0; i < 8; ++i) {
            float4 t = pf[i]; v[i] = t;
            s  += (t.x + t.y) + (t.z + t.w);
            ss += (t.x*t.x + t.y*t.y) + (t.z*t.z + t.w*t.w);
        }
        s  += __shfl_xor(s, 1);  s  += __shfl_xor(s, 2);
        ss += __shfl_xor(ss, 1); ss += __shfl_xor(ss, 2);
        const float mu   = s * (1.f / 128.f);
        const float rstd = rsqrtf(ss * (1.f / 128.f) - mu * mu + 1e-5f);
        const float4* pg = (const float4*)(gf  + (q << 5));
        const float4* pb = (const float4*)(btf + (q << 5));
        #pragma unroll
        for (int i = 0; i < 8; ++i) {
            float4 g = pg[i], bb = pb[i], t = v[i];
            h2t pA, pB;
            pA.x = (_Float16)fmaxf((t.x - mu) * rstd * g.x + bb.x, 0.f);
            pA.y = (_Float16)fmaxf((t.y - mu) * rstd * g.y + bb.y, 0.f);
            pB.x = (_Float16)fmaxf((t.z - mu) * rstd * g.z + bb.z, 0.f);
            pB.y = (_Float16)fmaxf((t.w - mu) * rstd * g.w + bb.w, 0.f);
            uint2 u;
            u.x = __builtin_bit_cast(unsigned int, pA);
            u.y = __builtin_bit_cast(unsigned int, pB);
            *(uint2*)&zh[r][(q << 5) + i * 4] = u;
        }
    }
    __syncthreads();

    {
        const int n0 = wv * 96;
        f16x8 bz[4][4];
        #pragma unroll
        for (int mt = 0; mt < 4; ++mt)
            #pragma unroll
            for (int ks = 0; ks < 4; ++ks)
                bz[mt][ks] = *(const f16x8*)&zh[mt*16 + lo][ks*32 + hi*8];
        #pragma unroll
        for (int nt = 0; nt < 6; ++nt) {
            const int nb = n0 + nt * 16;
            const float4 b4 = *(const float4*)(bih + nb + (hi << 2));
            const float* wr = Wih + (size_t)(nb + lo) * HH;
            f32x4 acc[4];
            #pragma unroll
            for (int mt = 0; mt < 4; ++mt) {
                acc[mt][0]=0.f; acc[mt][1]=0.f; acc[mt][2]=0.f; acc[mt][3]=0.f;
            }
            #pragma unroll
            for (int ks = 0; ks < 4; ++ks) {
                const float4* wp = (const float4*)(wr + ks*32 + hi*8);
                float4 w0 = wp[0], w1 = wp[1];
                f16x8 af;
                af[0]=(_Float16)w0.x; af[1]=(_Float16)w0.y; af[2]=(_Float16)w0.z; af[3]=(_Float16)w0.w;
                af[4]=(_Float16)w1.x; af[5]=(_Float16)w1.y; af[6]=(_Float16)w1.z; af[7]=(_Float16)w1.w;
                #pragma unroll
                for (int mt = 0; mt < 4; ++mt)
                    acc[mt] = __builtin_amdgcn_mfma_f32_16x16x32_f16(af, bz[mt][ks], acc[mt], 0, 0, 0);
            }
            #pragma unroll
            for (int mt = 0; mt < 4; ++mt) {
                h2t pA, pB;
                pA.x = (_Float16)(acc[mt][0] + b4.x);
                pA.y = (_Float16)(acc[mt][1] + b4.y);
                pB.x = (_Float16)(acc[mt][2] + b4.z);
                pB.y = (_Float16)(acc[mt][3] + b4.w);
                uint2 u;
                u.x = __builtin_bit_cast(unsigned int, pA);
                u.y = __builtin_bit_cast(unsigned int, pB);
                *(uint2*)(gxws + (m0 + (size_t)(mt*16 + lo)) * 384 + nb + (hi << 2)) = u;
            }
        }
    }
}

// ======================= PHASE 2 (MFMA recurrence, lean) =======================
// 256 blocks x 768 threads. Waves 0-7: mfma matvec + fused gates (chain=lo&1).
// Waves 8-11: gx staging only. hnew streamed to ws for p3.
__global__ void __launch_bounds__(768, 3) p2_kernel(
    const float* __restrict__ hx,  const int* __restrict__ done,
    const float* __restrict__ Whh, const float* __restrict__ bhh,
    unsigned short* __restrict__ gxws, float* __restrict__ out)
{
    const int tid = threadIdx.x;
    const int blk = blockIdx.x;

    __shared__ __align__(16) _Float16 hsh16[2][2][160];      // [buf][chain][pad160]
    __shared__ __align__(16) _Float16 gxb[2][2][CK][384];    // [chain][buf][t][3H] 48 KB
    __shared__ int dsh[2][TT];

    const int lo = tid & 15;
    const int hi = (tid & 63) >> 4;
    const int wv = tid >> 6;          // 0..11
    const int Y  = lo & 1;            // chain owned by this mfma lane
    const int d0 = (wv & 7) * 16 + hi * 4;

    // ---- mfma-wave persistent state: Whh A-frags + bias + hprev ----
    f16x8 aW[3][4];
    f32x4 bias[3];
    float hp[4];
    if (tid < 512) {
        #pragma unroll
        for (int q = 0; q < 3; ++q) {
            const float* wr = Whh + (size_t)(q * 128 + (wv & 7) * 16 + lo) * HH;
            #pragma unroll
            for (int ks = 0; ks < 4; ++ks) {
                const float4* wp = (const float4*)(wr + ks * 32 + hi * 8);
                float4 w0 = wp[0], w1 = wp[1];
                f16x8 t;
                t[0]=(_Float16)w0.x; t[1]=(_Float16)w0.y; t[2]=(_Float16)w0.z; t[3]=(_Float16)w0.w;
                t[4]=(_Float16)w1.x; t[5]=(_Float16)w1.y; t[6]=(_Float16)w1.z; t[7]=(_Float16)w1.w;
                aW[q][ks] = t;
            }
            bias[q] = *(const f32x4*)&bhh[q * 128 + (wv & 7) * 16 + hi * 4];
        }
        const float4 h4 = *(const float4*)&hx[(size_t)(2 * blk + Y) * HH + d0];
        hp[0]=h4.x; hp[1]=h4.y; hp[2]=h4.z; hp[3]=h4.w;
    }

    if (tid < 256) {
        const int Yc = tid >> 7, d = tid & 127;
        hsh16[0][Yc][d] = (_Float16)hx[(size_t)(2 * blk + Yc) * HH + d];
    }
    for (int idx = tid; idx < 2 * TT; idx += 768)
        dsh[idx >> 9][idx & 511] = done[(2 * blk + (idx >> 9)) * TT + (idx & 511)];

    // ---- gx staging: waves 8-11 (256 threads), 6 ushort4/chain/chunk ----
    const bool isStg = (tid >= 512);
    const int  sSt = tid - 512;
    const unsigned short* baseA = gxws + (size_t)(2 * blk + 0) * TT * 384;
    const unsigned short* baseB = gxws + (size_t)(2 * blk + 1) * TT * 384;
    ushort4 rA0, rA1, rA2, rA3, rA4, rA5, rB0, rB1, rB2, rB3, rB4, rB5;
    if (isStg) {   // chunk 0 -> buffer 0
        const ushort4* ca = (const ushort4*)baseA;
        const ushort4* cb = (const ushort4*)baseB;
        rA0=ca[0*256+sSt]; rA1=ca[1*256+sSt]; rA2=ca[2*256+sSt];
        rA3=ca[3*256+sSt]; rA4=ca[4*256+sSt]; rA5=ca[5*256+sSt];
        rB0=cb[0*256+sSt]; rB1=cb[1*256+sSt]; rB2=cb[2*256+sSt];
        rB3=cb[3*256+sSt]; rB4=cb[4*256+sSt]; rB5=cb[5*256+sSt];
        ushort4* ga = (ushort4*)&gxb[0][0][0][0];
        ushort4* gb = (ushort4*)&gxb[1][0][0][0];
        ga[0*256+sSt]=rA0; ga[1*256+sSt]=rA1; ga[2*256+sSt]=rA2;
        ga[3*256+sSt]=rA3; ga[4*256+sSt]=rA4; ga[5*256+sSt]=rA5;
        gb[0*256+sSt]=rB0; gb[1*256+sSt]=rB1; gb[2*256+sSt]=rB2;
        gb[3*256+sSt]=rB3; gb[4*256+sSt]=rB4; gb[5*256+sSt]=rB5;
    }
    __syncthreads();

    for (int c = 0; c < NCK; ++c) {
        if (isStg && c + 1 < NCK) {   // issue next-chunk loads (16-step slack)
            const ushort4* ca = (const ushort4*)(baseA + (size_t)(c + 1) * CK * 384);
            const ushort4* cb = (const ushort4*)(baseB + (size_t)(c + 1) * CK * 384);
            rA0=ca[0*256+sSt]; rA1=ca[1*256+sSt]; rA2=ca[2*256+sSt];
            rA3=ca[3*256+sSt]; rA4=ca[4*256+sSt]; rA5=ca[5*256+sSt];
            rB0=cb[0*256+sSt]; rB1=cb[1*256+sSt]; rB2=cb[2*256+sSt];
            rB3=cb[3*256+sSt]; rB4=cb[4*256+sSt]; rB5=cb[5*256+sSt];
        }
        for (int j = 0; j < CK; ++j) {
            const int t = c * CK + j;
            if (tid < 512) {
                const _Float16* hb = hsh16[t & 1][Y];
                f16x8 B0 = *(const f16x8*)&hb[0  + hi*8];
                f16x8 B1 = *(const f16x8*)&hb[32 + hi*8];
                f16x8 B2 = *(const f16x8*)&hb[64 + hi*8];
                f16x8 B3 = *(const f16x8*)&hb[96 + hi*8];
                const _Float16* gxp = gxb[Y][c & 1][j];
                f16x4 g0 = *(const f16x4*)&gxp[d0];
                f16x4 g1 = *(const f16x4*)&gxp[128 + d0];
                f16x4 g2 = *(const f16x4*)&gxp[256 + d0];
                const float mask = dsh[Y][t] ? 0.f : 1.f;
                f32x4 a0 = bias[0], a1 = bias[1], a2 = bias[2];
                a0 = __builtin_amdgcn_mfma_f32_16x16x32_f16(aW[0][0], B0, a0, 0, 0, 0);
                a1 = __builtin_amdgcn_mfma_f32_16x16x32_f16(aW[1][0], B0, a1, 0, 0, 0);
                a2 = __builtin_amdgcn_mfma_f32_16x16x32_f16(aW[2][0], B0, a2, 0, 0, 0);
                a0 = __builtin_amdgcn_mfma_f32_16x16x32_f16(aW[0][1], B1, a0, 0, 0, 0);
                a1 = __builtin_amdgcn_mfma_f32_16x16x32_f16(aW[1][1], B1, a1, 0, 0, 0);
                a2 = __builtin_amdgcn_mfma_f32_16x16x32_f16(aW[2][1], B1, a2, 0, 0, 0);
                a0 = __builtin_amdgcn_mfma_f32_16x16x32_f16(aW[0][2], B2, a0, 0, 0, 0);
                a1 = __builtin_amdgcn_mfma_f32_16x16x32_f16(aW[1][2], B2, a1, 0, 0, 0);
                a2 = __builtin_amdgcn_mfma_f32_16x16x32_f16(aW[2][2], B2, a2, 0, 0, 0);
                a0 = __builtin_amdgcn_mfma_f32_16x16x32_f16(aW[0][3], B3, a0, 0, 0, 0);
                a1 = __builtin_amdgcn_mfma_f32_16x16x32_f16(aW[1][3], B3, a1, 0, 0, 0);
                a2 = __builtin_amdgcn_mfma_f32_16x16x32_f16(aW[2][3], B3, a2, 0, 0, 0);
                // fused gates (rcpf-based sigmoid/tanh); lane owns d0..d0+3 of chain Y
                float hnA[4], hmA[4];
                #pragma unroll
                for (int jj = 0; jj < 4; ++jj) {
                    float xr = (float)g0[jj] + a0[jj];
                    float xz = (float)g1[jj] + a1[jj];
                    float r_ = __builtin_amdgcn_rcpf(1.f + __expf(-xr));
                    float u_ = __builtin_amdgcn_rcpf(1.f + __expf(-xz));
                    float a_ = (float)g2[jj] + r_ * a2[jj];
                    a_ = fminf(fmaxf(a_, -20.f), 20.f);
                    float e2 = __expf(2.f * a_);
                    float nn = 1.f - 2.f * __builtin_amdgcn_rcpf(e2 + 1.f);
                    float hnew = (1.f - u_) * nn + u_ * hp[jj];
                    float hm = hnew * mask;
                    hp[jj] = hm;
                    hnA[jj] = hnew;
                    hmA[jj] = hm;
                }
                if (lo < 2) {
                    // stream hnew (pre-mask) to ws for p3 (fp32, in gxws slot)
                    float* hw = (float*)(gxws + ((size_t)(2 * blk + Y) * TT + t) * 384);
                    *(float4*)&hw[d0] = make_float4(hnA[0], hnA[1], hnA[2], hnA[3]);
                    h2t p0, p1v;
                    p0.x  = (_Float16)hmA[0]; p0.y  = (_Float16)hmA[1];
                    p1v.x = (_Float16)hmA[2]; p1v.y = (_Float16)hmA[3];
                    uint2 u;
                    u.x = __builtin_bit_cast(unsigned int, p0);
                    u.y = __builtin_bit_cast(unsigned int, p1v);
                    *(uint2*)&hsh16[(t + 1) & 1][Y][d0] = u;
                    if (t == TT - 1) {
                        *(float4*)&out[HFIN + (size_t)(2 * blk + Y) * HH + d0] =
                            make_float4(hmA[0], hmA[1], hmA[2], hmA[3]);
                    }
                }
            }
            if (isStg && j == CK - 1 && c + 1 < NCK) {  // write into opposite buffer
                const int nb = (c + 1) & 1;
                ushort4* ga = (ushort4*)&gxb[0][nb][0][0];
                ushort4* gb = (ushort4*)&gxb[1][nb][0][0];
                ga[0*256+sSt]=rA0; ga[1*256+sSt]=rA1; ga[2*256+sSt]=rA2;
                ga[3*256+sSt]=rA3; ga[4*256+sSt]=rA4; ga[5*256+sSt]=rA5;
                gb[0*256+sSt]=rB0; gb[1*256+sSt]=rB1; gb[2*256+sSt]=rB2;
                gb[3*256+sSt]=rB3; gb[4*256+sSt]=rB4; gb[5*256+sSt]=rB5;
            }
            BAR();
        }
    }
}

// ======================= PHASE 3 (LN + heads, wide) =======================
// 4096 blocks x 256 threads; 64 rows each. Thread q of a row-quad owns
// float4-chunks c with c%4==q (interleaved -> conflict-free wpl reads).
__global__ void __launch_bounds__(256, 2) p3_kernel(
    const unsigned short* __restrict__ gxws,
    const float* __restrict__ gr,  const float* __restrict__ btr,
    const float* __restrict__ Wp,  const float* __restrict__ bp,
    const float* __restrict__ Wv,  const float* __restrict__ bv,
    float* __restrict__ out)
{
    const int tid = threadIdx.x;
    __shared__ __align__(16) float wpl[9][132];
    __shared__ float bpl[9];

    for (int idx = tid; idx < 9 * HH; idx += 256) {
        int row = idx >> 7, col = idx & 127;
        wpl[row][col] = (row < 8) ? Wp[row * HH + col] : Wv[col];
    }
    if (tid < 9) bpl[tid] = (tid < 8) ? bp[tid] : bv[0];

    const size_t m = (size_t)blockIdx.x * 64 + (tid >> 2);
    const int q = tid & 3;
    const float* hr = (const float*)(gxws + m * 384);

    float4 v[8];
    float s = 0.f, ss = 0.f;
    #pragma unroll
    for (int j = 0; j < 8; ++j) {
        float4 t = ((const float4*)hr)[q + 4 * j];
        v[j] = t;
        s  += (t.x + t.y) + (t.z + t.w);
        ss += (t.x*t.x + t.y*t.y) + (t.z*t.z + t.w*t.w);
    }
    s  += __shfl_xor(s, 1);  s  += __shfl_xor(s, 2);
    ss += __shfl_xor(ss, 1); ss += __shfl_xor(ss, 2);
    const float mu   = s * (1.f / 128.f);
    const float rstd = rsqrtf(ss * (1.f / 128.f) - mu * mu + 1e-5f);

    float4 y[8];
    #pragma unroll
    for (int j = 0; j < 8; ++j) {
        float4 g  = ((const float4*)gr)[q + 4 * j];
        float4 bb = ((const float4*)btr)[q + 4 * j];
        float4 t = v[j];
        y[j].x = (t.x - mu) * rstd * g.x + bb.x;
        y[j].y = (t.y - mu) * rstd * g.y + bb.y;
        y[j].z = (t.z - mu) * rstd * g.z + bb.z;
        y[j].w = (t.w - mu) * rstd * g.w + bb.w;
    }
    __syncthreads();   // wpl staged

    float acc[9];
    #pragma unroll
    for (int hd = 0; hd < 9; ++hd) {
        float a = 0.f;
        #pragma unroll
        for (int j = 0; j < 8; ++j) {
            float4 w = ((const float4*)wpl[hd])[q + 4 * j];
            a += (y[j].x * w.x + y[j].y * w.y) + (y[j].z * w.z + y[j].w * w.w);
        }
        acc[hd] = a;
    }
    #pragma unroll
    for (int hd = 0; hd < 9; ++hd) {
        acc[hd] += __shfl_xor(acc[hd], 1);
        acc[hd] += __shfl_xor(acc[hd], 2);
    }
    if (q == 0) {
        float4 o0 = make_float4(acc[0] + bpl[0], acc[1] + bpl[1], acc[2] + bpl[2], acc[3] + bpl[3]);
        float4 o1 = make_float4(acc[4] + bpl[4], acc[5] + bpl[5], acc[6] + bpl[6], acc[7] + bpl[7]);
        ((float4*)(out + m * AA))[0] = o0;
        ((float4*)(out + m * AA))[1] = o1;
    } else if (q == 1) {
        out[VALO + m] = acc[8] + bpl[8];
    }
}

extern "C" void kernel_launch(void* const* d_in, const int* in_sizes, int n_in,
                              void* d_out, int out_size, void* d_ws, size_t ws_size,
                              hipStream_t stream) {
    const float* x   = (const float*)d_in[0];
    const float* hx  = (const float*)d_in[1];
    const int*   dn  = (const int*)d_in[2];
    const float* Wf  = (const float*)d_in[3];
    const float* bfe = (const float*)d_in[4];
    const float* gf  = (const float*)d_in[5];
    const float* btf = (const float*)d_in[6];
    const float* Wih = (const float*)d_in[7];
    const float* Whh = (const float*)d_in[8];
    const float* bih = (const float*)d_in[9];
    const float* bhh = (const float*)d_in[10];
    const float* gr  = (const float*)d_in[11];
    const float* btr = (const float*)d_in[12];
    const float* Wp  = (const float*)d_in[13];
    const float* bp  = (const float*)d_in[14];
    const float* Wv  = (const float*)d_in[15];
    const float* bv  = (const float*)d_in[16];
    float* out = (float*)d_out;

    unsigned short* gxws = (unsigned short*)d_ws;   // 201.3 MB gx buffer (+hraw reuse)
    hipLaunchKernelGGL(p1_kernel, dim3(BB * TT / 64), dim3(256), 0, stream,
                       x, Wf, bfe, gf, btf, Wih, bih, gxws);
    hipLaunchKernelGGL(p2_kernel, dim3(BB / 2), dim3(768), 0, stream,
                       hx, dn, Whh, bhh, gxws, out);
    hipLaunchKernelGGL(p3_kernel, dim3(BB * TT / 64), dim3(256), 0, stream,
                       gxws, gr, btr, Wp, bp, Wv, bv, out);
}